// Round 1
// baseline (442.406 us; speedup 1.0000x reference)
//
#include <hip/hip_runtime.h>

typedef __attribute__((ext_vector_type(8))) __bf16 bf16x8;
typedef __attribute__((ext_vector_type(8))) unsigned short ushort8;
typedef __attribute__((ext_vector_type(4))) float floatx4;

#define WAVES 4
#define MT 2                 // m-tiles (16 rows each) per iteration -> 32 rows
#define ITERS 2
#define ROWS_PER_BLOCK (WAVES * ITERS * MT * 16)  // 256

// fp32 -> bf16, round-to-nearest-even (inputs are finite; no NaN handling needed)
__device__ __forceinline__ unsigned short f2bf(float f) {
    unsigned u = __builtin_bit_cast(unsigned, f);
    u += 0x7fff + ((u >> 16) & 1);
    return (unsigned short)(u >> 16);
}

__global__ __launch_bounds__(256) void OrthogonalTransform_kernel(
        const float* __restrict__ x, const float* __restrict__ rot,
        float* __restrict__ out) {
    // B fragments, fragment-major: frag f=(c*8+nt), lane l, elem j -> bt[(f*64+l)*8+j]
    // holds B[k = 32c + (l>>4)*8 + j][n = 16nt + (l&15)] as bf16.
    __shared__ __align__(16) unsigned short bt[32 * 64 * 8];   // 32 KB

    const int tid = threadIdx.x;

    // ---- stage R into LDS (coalesced float4 reads; once per block) ----
    #pragma unroll
    for (int i = 0; i < 16; ++i) {
        int q = i * 256 + tid;          // 0..4095 = 128 k-rows x 32 float4 groups
        int g = q & 31;                 // float4 group along n
        int k = q >> 5;                 // 0..127
        floatx4 v = *(const floatx4*)(rot + k * 128 + g * 4);
        int c  = k >> 5;
        int ql = (k >> 3) & 3;          // quad within k-chunk
        int j  = k & 7;
        int nt = g >> 2;                // n-tile (16 cols); 4 groups of 4 per tile
        int base = ((c * 8 + nt) * 64 + ql * 16) * 8 + j;
        int lo0 = (g & 3) * 4;          // n&15 of first element
        bt[base + (lo0 + 0) * 8] = f2bf(v[0]);
        bt[base + (lo0 + 1) * 8] = f2bf(v[1]);
        bt[base + (lo0 + 2) * 8] = f2bf(v[2]);
        bt[base + (lo0 + 3) * 8] = f2bf(v[3]);
    }
    __syncthreads();

    const int lane = tid & 63;
    const int wave = tid >> 6;
    const int m    = lane & 15;
    const int quad = lane >> 4;
    const long wave_row0 = ((long)blockIdx.x * WAVES + wave) * (long)(ITERS * MT * 16);

    for (int it = 0; it < ITERS; ++it) {
        const long row0 = wave_row0 + it * (MT * 16);

        // ---- load A (fp32, MFMA A-layout: m=lane&15, k=32c+quad*8+j) ----
        floatx4 araw[MT][4][2];
        #pragma unroll
        for (int t = 0; t < MT; ++t)
            #pragma unroll
            for (int c = 0; c < 4; ++c) {
                const float* p = x + (row0 + t * 16 + m) * 128 + c * 32 + quad * 8;
                araw[t][c][0] = *(const floatx4*)p;
                araw[t][c][1] = *(const floatx4*)(p + 4);
            }

        // ---- convert to bf16 fragments ----
        bf16x8 af[MT][4];
        #pragma unroll
        for (int t = 0; t < MT; ++t)
            #pragma unroll
            for (int c = 0; c < 4; ++c) {
                ushort8 a;
                #pragma unroll
                for (int e = 0; e < 4; ++e) {
                    a[e]     = f2bf(araw[t][c][0][e]);
                    a[e + 4] = f2bf(araw[t][c][1][e]);
                }
                af[t][c] = __builtin_bit_cast(bf16x8, a);
            }

        // ---- MFMA: 2 m-tiles x 8 n-tiles x 4 k-chunks ----
        floatx4 acc[MT][8];
        #pragma unroll
        for (int t = 0; t < MT; ++t)
            #pragma unroll
            for (int nt = 0; nt < 8; ++nt)
                acc[t][nt] = (floatx4){0.f, 0.f, 0.f, 0.f};

        #pragma unroll
        for (int nt = 0; nt < 8; ++nt) {
            #pragma unroll
            for (int c = 0; c < 4; ++c) {
                bf16x8 bfrag = *(const bf16x8*)&bt[((c * 8 + nt) * 64 + lane) * 8];
                #pragma unroll
                for (int t = 0; t < MT; ++t)
                    acc[t][nt] = __builtin_amdgcn_mfma_f32_16x16x32_bf16(
                        af[t][c], bfrag, acc[t][nt], 0, 0, 0);
            }
        }

        // ---- store C (C/D layout: row = quad*4 + reg, col = lane&15) ----
        #pragma unroll
        for (int t = 0; t < MT; ++t) {
            const long srow = row0 + t * 16 + quad * 4;
            #pragma unroll
            for (int r = 0; r < 4; ++r) {
                float* po = out + (srow + r) * 128 + (lane & 15);
                #pragma unroll
                for (int nt = 0; nt < 8; ++nt)
                    po[nt * 16] = acc[t][nt][r];
            }
        }
    }
}

extern "C" void kernel_launch(void* const* d_in, const int* in_sizes, int n_in,
                              void* d_out, int out_size, void* d_ws, size_t ws_size,
                              hipStream_t stream) {
    const float* x   = (const float*)d_in[0];
    const float* rot = (const float*)d_in[1];
    float* out = (float*)d_out;

    const long M = (long)in_sizes[0] / 128;        // 524288 rows of 128
    const int grid = (int)(M / ROWS_PER_BLOCK);    // 2048 blocks
    OrthogonalTransform_kernel<<<grid, 256, 0, stream>>>(x, rot, out);
}